// Round 1
// baseline (289.947 us; speedup 1.0000x reference)
//
#include <hip/hip_runtime.h>
#include <math.h>

#define C_IN 2048
#define N_EXP 64
#define TOK_PER_BLK 16

// Block: 256 threads = 4 waves. Block owns 16 tokens.
// Phase 1: wave w computes partial logits over C-chunk [w*512, (w+1)*512).
//   Lane l: eg = l&15 (experts eg*4..eg*4+3), tg = l>>4 (tokens tg*4..tg*4+3).
//   16 fp32 accumulators/lane, float4 global loads (8 loads : 64 FMAs).
// Phase 2: wave w handles tokens w*4..w*4+3; lane = expert index.
//   Butterfly max/argmax (tie -> lower index, matches jax.lax.top_k),
//   exp-sum, masked 2nd max, scatter p1/p2/0.
__global__ __launch_bounds__(256, 4) void topk_gate_kernel(
    const float* __restrict__ x, const float* __restrict__ W,
    const float* __restrict__ b, float* __restrict__ out, int tokens)
{
    __shared__ float part[4][TOK_PER_BLK][N_EXP];

    const int tid = threadIdx.x;
    const int w = tid >> 6;        // wave id 0..3
    const int l = tid & 63;        // lane
    const int eg = l & 15;         // expert group
    const int tg = l >> 4;         // token group
    const int tokBase = blockIdx.x * TOK_PER_BLK;

    float acc[4][4];
#pragma unroll
    for (int i = 0; i < 4; ++i)
#pragma unroll
        for (int j = 0; j < 4; ++j) acc[i][j] = 0.0f;

    const int c0 = w * (C_IN / 4);               // this wave's 512-col chunk
    const float* xb = x + (size_t)tokBase * C_IN + c0;
    const float* wb = W + c0;

    for (int s = 0; s < (C_IN / 4) / 4; ++s) {   // 128 steps of 4 columns
        const int c = s * 4;
        float4 xv[4], wv[4];
#pragma unroll
        for (int i = 0; i < 4; ++i)
            xv[i] = *(const float4*)(xb + (size_t)(tg * 4 + i) * C_IN + c);
#pragma unroll
        for (int j = 0; j < 4; ++j)
            wv[j] = *(const float4*)(wb + (size_t)(eg * 4 + j) * C_IN + c);
#pragma unroll
        for (int i = 0; i < 4; ++i)
#pragma unroll
            for (int j = 0; j < 4; ++j) {
                acc[i][j] += xv[i].x * wv[j].x + xv[i].y * wv[j].y
                           + xv[i].z * wv[j].z + xv[i].w * wv[j].w;
            }
    }

#pragma unroll
    for (int i = 0; i < 4; ++i)
#pragma unroll
        for (int j = 0; j < 4; ++j)
            part[w][tg * 4 + i][eg * 4 + j] = acc[i][j];
    __syncthreads();

    // ---- Phase 2: softmax + top-2 scatter ----
    const int e = l;               // lane = expert
    const float be = b[e];
    for (int ti = 0; ti < 4; ++ti) {
        const int t = w * 4 + ti;
        float logit = part[0][t][e] + part[1][t][e]
                    + part[2][t][e] + part[3][t][e] + be;

        // top-1 with argmax; tie -> lower index (jax.lax.top_k is stable)
        float v1 = logit; int i1 = e;
#pragma unroll
        for (int off = 32; off >= 1; off >>= 1) {
            float ov = __shfl_xor(v1, off, 64);
            int   oi = __shfl_xor(i1, off, 64);
            if (ov > v1 || (ov == v1 && oi < i1)) { v1 = ov; i1 = oi; }
        }

        // softmax denominator
        float ex = expf(logit - v1);
        float ssum = ex;
#pragma unroll
        for (int off = 32; off >= 1; off >>= 1)
            ssum += __shfl_xor(ssum, off, 64);

        // top-2: mask out i1, reduce again
        float v2 = (e == i1) ? -3.4e38f : logit;
        int   i2 = (e == i1) ? N_EXP : e;
#pragma unroll
        for (int off = 32; off >= 1; off >>= 1) {
            float ov = __shfl_xor(v2, off, 64);
            int   oi = __shfl_xor(i2, off, 64);
            if (ov > v2 || (ov == v2 && oi < i2)) { v2 = ov; i2 = oi; }
        }

        const float inv = 1.0f / ssum;
        const float p1 = inv;                       // exp(0)/sum
        const float p2 = expf(v2 - v1) * inv;
        const float o = (e == i1) ? p1 : ((e == i2) ? p2 : 0.0f);
        out[(size_t)(tokBase + t) * N_EXP + e] = o;
    }
}

extern "C" void kernel_launch(void* const* d_in, const int* in_sizes, int n_in,
                              void* d_out, int out_size, void* d_ws, size_t ws_size,
                              hipStream_t stream) {
    const float* x = (const float*)d_in[0];   // [4,4096,2048]
    const float* W = (const float*)d_in[1];   // [64,2048]
    const float* b = (const float*)d_in[2];   // [64]
    float* out = (float*)d_out;               // [4,4096,64]

    const int tokens = in_sizes[0] / C_IN;    // 16384
    const int grid = tokens / TOK_PER_BLK;    // 1024
    topk_gate_kernel<<<grid, 256, 0, stream>>>(x, W, b, out, tokens);
}

// Round 2
// 89.311 us; speedup vs baseline: 3.2465x; 3.2465x over previous
//
#include <hip/hip_runtime.h>
#include <math.h>

#define C_IN 2048
#define N_EXP 64
#define TOK_PER_BLK 16
#define BK 64
#define NROUND (C_IN / BK)   // 32

// Block: 256 threads = 4 waves, owns 16 tokens x 64 experts, K double-buffered
// through LDS in 64-col rounds.
//   Staging (coalesced): thread tid loads 1 float4 of x-tile + 4 float4 of
//   W-tile per round; stored to LDS with XOR unit-swizzle u ^= (row & 15)
//   (unit = 16B column block) so compute-phase reads are 2-way max (free).
//   Compute: wave w owns k-units w*4..w*4+3 of each round. Lane l: tg=l>>4
//   (tokens tg*4+i), eg=l&15 (experts eg+16j). acc[4][4]; per unit:
//   4+4 ds_read_b128 -> 64 FMA.
//   x-read: 4 distinct addrs, 16-lane broadcast. W-read: 16 distinct addrs
//   (banks spread by swizzle), 4-lane broadcast.
// Phase 2: cross-wave partial reduce via LDS (aliased on ws), then wave-per-
// token softmax + top-2 scatter (identical to the verified round-1 epilogue).
__global__ __launch_bounds__(256, 4) void topk_gate_kernel(
    const float* __restrict__ x, const float* __restrict__ W,
    const float* __restrict__ b, float* __restrict__ out)
{
    __shared__ float xs[2][TOK_PER_BLK][BK];   // 8 KB
    __shared__ float ws[2][N_EXP][BK];         // 32 KB

    const int tid = threadIdx.x;
    const int w  = tid >> 6;       // wave 0..3
    const int l  = tid & 63;
    const int eg = l & 15;         // expert low bits: experts eg+16j
    const int tg = l >> 4;         // token group: tokens tg*4+i
    const int tokBase = blockIdx.x * TOK_PER_BLK;

    // staging mapping
    const int rx = tid >> 4;       // x-tile row 0..15
    const int ux = tid & 15;       // x-tile 16B-unit 0..15

    float acc[4][4] = {};
    float4 xr, wr[4];

    const float* xg = x + (size_t)tokBase * C_IN;

    // ---- prologue: stage round 0 into buffer 0 ----
    xr = *(const float4*)(xg + (size_t)rx * C_IN + ux * 4);
#pragma unroll
    for (int t = 0; t < 4; ++t) {
        const int flat = tid + 256 * t;
        wr[t] = *(const float4*)(W + (size_t)(flat >> 4) * C_IN + (flat & 15) * 4);
    }
    *(float4*)&xs[0][rx][(ux ^ (rx & 15)) * 4] = xr;
#pragma unroll
    for (int t = 0; t < 4; ++t) {
        const int flat = tid + 256 * t;
        const int rw = flat >> 4, uw = flat & 15;
        *(float4*)&ws[0][rw][(uw ^ (rw & 15)) * 4] = wr[t];
    }
    __syncthreads();

    for (int r = 0; r < NROUND; ++r) {
        const int cur = r & 1;
        // issue next round's global loads early (latency hides under compute)
        if (r + 1 < NROUND) {
            const int c0 = (r + 1) * BK;
            xr = *(const float4*)(xg + (size_t)rx * C_IN + c0 + ux * 4);
#pragma unroll
            for (int t = 0; t < 4; ++t) {
                const int flat = tid + 256 * t;
                wr[t] = *(const float4*)(W + (size_t)(flat >> 4) * C_IN + c0 + (flat & 15) * 4);
            }
        }
        // compute this wave's 16 k-columns of the round
#pragma unroll
        for (int it = 0; it < 4; ++it) {
            const int u0 = w * 4 + it;
            float4 xv[4], wv[4];
#pragma unroll
            for (int i = 0; i < 4; ++i) {
                const int tok = tg * 4 + i;
                xv[i] = *(const float4*)&xs[cur][tok][(u0 ^ tok) * 4];
            }
#pragma unroll
            for (int j = 0; j < 4; ++j) {
                const int e = eg + 16 * j;
                wv[j] = *(const float4*)&ws[cur][e][(u0 ^ eg) * 4];
            }
#pragma unroll
            for (int i = 0; i < 4; ++i)
#pragma unroll
            for (int j = 0; j < 4; ++j) {
                acc[i][j] = fmaf(xv[i].x, wv[j].x, acc[i][j]);
                acc[i][j] = fmaf(xv[i].y, wv[j].y, acc[i][j]);
                acc[i][j] = fmaf(xv[i].z, wv[j].z, acc[i][j]);
                acc[i][j] = fmaf(xv[i].w, wv[j].w, acc[i][j]);
            }
        }
        // write next buffer (readers of it finished before previous barrier)
        if (r + 1 < NROUND) {
            const int nxt = cur ^ 1;
            *(float4*)&xs[nxt][rx][(ux ^ (rx & 15)) * 4] = xr;
#pragma unroll
            for (int t = 0; t < 4; ++t) {
                const int flat = tid + 256 * t;
                const int rw = flat >> 4, uw = flat & 15;
                *(float4*)&ws[nxt][rw][(uw ^ (rw & 15)) * 4] = wr[t];
            }
        }
        __syncthreads();
    }

    // ---- cross-wave partial reduction (part aliases ws: 16 KB of 32 KB) ----
    float (*part)[TOK_PER_BLK][N_EXP] = (float (*)[TOK_PER_BLK][N_EXP])ws;
#pragma unroll
    for (int i = 0; i < 4; ++i)
#pragma unroll
    for (int j = 0; j < 4; ++j)
        part[w][tg * 4 + i][eg + 16 * j] = acc[i][j];
    __syncthreads();

    // ---- Phase 2: softmax + top-2 scatter (verified round-1 epilogue) ----
    const int e = l;               // lane = expert
    const float be = b[e];
    for (int ti = 0; ti < 4; ++ti) {
        const int t = w * 4 + ti;
        float logit = part[0][t][e] + part[1][t][e]
                    + part[2][t][e] + part[3][t][e] + be;

        // top-1 argmax; tie -> lower index (jax.lax.top_k stable)
        float v1 = logit; int i1 = e;
#pragma unroll
        for (int off = 32; off >= 1; off >>= 1) {
            float ov = __shfl_xor(v1, off, 64);
            int   oi = __shfl_xor(i1, off, 64);
            if (ov > v1 || (ov == v1 && oi < i1)) { v1 = ov; i1 = oi; }
        }

        // softmax denominator
        float ex = expf(logit - v1);
        float ssum = ex;
#pragma unroll
        for (int off = 32; off >= 1; off >>= 1)
            ssum += __shfl_xor(ssum, off, 64);

        // top-2: mask out i1, reduce again
        float v2 = (e == i1) ? -3.4e38f : logit;
        int   i2 = (e == i1) ? N_EXP : e;
#pragma unroll
        for (int off = 32; off >= 1; off >>= 1) {
            float ov = __shfl_xor(v2, off, 64);
            int   oi = __shfl_xor(i2, off, 64);
            if (ov > v2 || (ov == v2 && oi < i2)) { v2 = ov; i2 = oi; }
        }

        const float inv = 1.0f / ssum;
        const float p1 = inv;
        const float p2 = expf(v2 - v1) * inv;
        const float o = (e == i1) ? p1 : ((e == i2) ? p2 : 0.0f);
        out[(size_t)(tokBase + t) * N_EXP + e] = o;
    }
}

extern "C" void kernel_launch(void* const* d_in, const int* in_sizes, int n_in,
                              void* d_out, int out_size, void* d_ws, size_t ws_size,
                              hipStream_t stream) {
    const float* x = (const float*)d_in[0];   // [4,4096,2048]
    const float* W = (const float*)d_in[1];   // [64,2048]
    const float* b = (const float*)d_in[2];   // [64]
    float* out = (float*)d_out;               // [4,4096,64]

    const int tokens = in_sizes[0] / C_IN;    // 16384
    const int grid = tokens / TOK_PER_BLK;    // 1024
    topk_gate_kernel<<<grid, 256, 0, stream>>>(x, W, b, out);
}

// Round 3
// 55.552 us; speedup vs baseline: 5.2194x; 1.6077x over previous
//
#include <hip/hip_runtime.h>
#include <math.h>

#define C_IN 2048
#define N_EXP 64
#define TPB 64            // tokens per block
#define BK 64             // K per chunk
#define NCH (C_IN / BK)   // 32 chunks
#define DELTA  3e-4f      // risky-gap threshold (>=100x expected logit error)
#define DELTA2 1e-3f      // candidate window around v2

typedef __bf16 bf16x8 __attribute__((ext_vector_type(8)));
typedef float f32x4 __attribute__((ext_vector_type(4)));

__device__ __forceinline__ ushort bf16_rne(float f) {
    uint u = __float_as_uint(f);
    u += 0x7FFFu + ((u >> 16) & 1u);
    return (ushort)(u >> 16);
}
__device__ __forceinline__ float bf16_f32(ushort h) {
    return __uint_as_float((uint)h << 16);
}

// Pre-kernel: W fp32 [64][2048] -> ws: wh bf16 + wl bf16 (residual), 512 KB.
__global__ void conv_w_kernel(const float* __restrict__ W,
                              ushort* __restrict__ wh, ushort* __restrict__ wl) {
    int i = blockIdx.x * 256 + threadIdx.x;   // grid 512*256 = 131072 elems
    float f = W[i];
    ushort h = bf16_rne(f);
    wh[i] = h;
    wl[i] = bf16_rne(f - bf16_f32(h));
}

// Main: block = 512 thr (8 waves), 64 tokens, all 64 experts, full K.
// Split-bf16 MFMA: logits = xh*wh + xl*wh + xh*wl (xl*wl dropped, ~2e-7).
// LDS tiles [row][BK] bf16 with XOR unit-swizzle (u ^= row&7, 16B units).
// Wave w: tb=w>>1 (16 tokens), eb=w&1 (32 experts = 2 N-frags).
// Epilogue: cross-wave via part LDS, wave-per-8-tokens softmax/top2 with
// exact-fp32 fix for tokens whose top gaps are < DELTA.
__global__ __launch_bounds__(512, 2) void topk_gate_kernel(
    const float* __restrict__ x, const float* __restrict__ Wf,
    const float* __restrict__ b, const ushort* __restrict__ wh_g,
    const ushort* __restrict__ wl_g, float* __restrict__ out)
{
    __shared__ ushort smem[4 * 2 * (N_EXP * BK)];   // 64 KB
    // carve: per-buf tiles of 4096 ushorts (8 KB) each
    #define XH(buf) (smem + (buf) * 4096)
    #define XL(buf) (smem + 8192 + (buf) * 4096)
    #define WH(buf) (smem + 16384 + (buf) * 4096)
    #define WL(buf) (smem + 24576 + (buf) * 4096)

    const int tid = threadIdx.x;
    const int w = tid >> 6, l = tid & 63;
    const int tokBase = blockIdx.x * TPB;

    // staging roles
    const int xt = tid >> 3;        // token 0..63 (8 thr/token)
    const int xq = tid & 7;         // thread's quads: xq and xq+8 (of 16)
    const int we = tid >> 3;        // expert 0..63
    const int wu = tid & 7;         // 16B unit 0..7

    // precomputed swizzled LDS elem offsets (ushort units)
    const int xd0 = (xt * 8 + ((xq >> 1) ^ (xt & 7))) * 8 + (xq & 1) * 4;
    const int q2 = xq + 8;
    const int xd1 = (xt * 8 + ((q2 >> 1) ^ (xt & 7))) * 8 + (q2 & 1) * 4;
    const int wd = (we * 8 + (wu ^ (we & 7))) * 8;

    // compute roles
    const int tb = w >> 1, eb = w & 1;
    const int arow = tb * 16 + (l & 15);
    const int br0 = eb * 32 + (l & 15);
    const int br1 = br0 + 16;
    const int kg = l >> 4;
    int a_off[2], b0_off[2], b1_off[2];
#pragma unroll
    for (int ks = 0; ks < 2; ++ks) {
        const int u = ks * 4 + kg;
        a_off[ks]  = (arow * 8 + (u ^ (arow & 7))) * 8;
        b0_off[ks] = (br0 * 8 + (u ^ (br0 & 7))) * 8;
        b1_off[ks] = (br1 * 8 + (u ^ (br1 & 7))) * 8;
    }

    const float* xg = x + (size_t)tokBase * C_IN;
    f32x4 acc0 = {0.f, 0.f, 0.f, 0.f};
    f32x4 acc1 = {0.f, 0.f, 0.f, 0.f};

    // ---- prologue: stage chunk 0 into buf 0 ----
    {
        float4 xv0 = *(const float4*)(xg + (size_t)xt * C_IN + xq * 4);
        float4 xv1 = *(const float4*)(xg + (size_t)xt * C_IN + q2 * 4);
        uint4 wv0 = *(const uint4*)(wh_g + (size_t)we * C_IN + wu * 8);
        uint4 wv1 = *(const uint4*)(wl_g + (size_t)we * C_IN + wu * 8);
        float fx[8] = {xv0.x, xv0.y, xv0.z, xv0.w, xv1.x, xv1.y, xv1.z, xv1.w};
        ushort hh[8], ll[8];
#pragma unroll
        for (int i = 0; i < 8; ++i) {
            hh[i] = bf16_rne(fx[i]);
            ll[i] = bf16_rne(fx[i] - bf16_f32(hh[i]));
        }
        uint2 hv0 = {(uint)hh[0] | ((uint)hh[1] << 16), (uint)hh[2] | ((uint)hh[3] << 16)};
        uint2 lv0 = {(uint)ll[0] | ((uint)ll[1] << 16), (uint)ll[2] | ((uint)ll[3] << 16)};
        uint2 hv1 = {(uint)hh[4] | ((uint)hh[5] << 16), (uint)hh[6] | ((uint)hh[7] << 16)};
        uint2 lv1 = {(uint)ll[4] | ((uint)ll[5] << 16), (uint)ll[6] | ((uint)ll[7] << 16)};
        *(uint2*)&XH(0)[xd0] = hv0; *(uint2*)&XL(0)[xd0] = lv0;
        *(uint2*)&XH(0)[xd1] = hv1; *(uint2*)&XL(0)[xd1] = lv1;
        *(uint4*)&WH(0)[wd] = wv0;  *(uint4*)&WL(0)[wd] = wv1;
    }
    __syncthreads();

    for (int r = 0; r < NCH; ++r) {
        const int cur = r & 1;
        float4 xv0, xv1; uint4 wv0, wv1;
        const bool more = (r + 1 < NCH);
        if (more) {   // issue next chunk's global loads early (T14)
            const int c0 = (r + 1) * BK;
            xv0 = *(const float4*)(xg + (size_t)xt * C_IN + c0 + xq * 4);
            xv1 = *(const float4*)(xg + (size_t)xt * C_IN + c0 + q2 * 4);
            wv0 = *(const uint4*)(wh_g + (size_t)we * C_IN + c0 + wu * 8);
            wv1 = *(const uint4*)(wl_g + (size_t)we * C_IN + c0 + wu * 8);
        }
        // ---- compute on buf cur: 12 ds_read_b128, 12 MFMA ----
#pragma unroll
        for (int ks = 0; ks < 2; ++ks) {
            bf16x8 ah = __builtin_bit_cast(bf16x8, *(const uint4*)&XH(cur)[a_off[ks]]);
            bf16x8 al = __builtin_bit_cast(bf16x8, *(const uint4*)&XL(cur)[a_off[ks]]);
            bf16x8 bh0 = __builtin_bit_cast(bf16x8, *(const uint4*)&WH(cur)[b0_off[ks]]);
            bf16x8 bl0 = __builtin_bit_cast(bf16x8, *(const uint4*)&WL(cur)[b0_off[ks]]);
            bf16x8 bh1 = __builtin_bit_cast(bf16x8, *(const uint4*)&WH(cur)[b1_off[ks]]);
            bf16x8 bl1 = __builtin_bit_cast(bf16x8, *(const uint4*)&WL(cur)[b1_off[ks]]);
            acc0 = __builtin_amdgcn_mfma_f32_16x16x32_bf16(ah, bh0, acc0, 0, 0, 0);
            acc1 = __builtin_amdgcn_mfma_f32_16x16x32_bf16(ah, bh1, acc1, 0, 0, 0);
            acc0 = __builtin_amdgcn_mfma_f32_16x16x32_bf16(al, bh0, acc0, 0, 0, 0);
            acc1 = __builtin_amdgcn_mfma_f32_16x16x32_bf16(al, bh1, acc1, 0, 0, 0);
            acc0 = __builtin_amdgcn_mfma_f32_16x16x32_bf16(ah, bl0, acc0, 0, 0, 0);
            acc1 = __builtin_amdgcn_mfma_f32_16x16x32_bf16(ah, bl1, acc1, 0, 0, 0);
        }
        if (more) {   // convert + LDS-write next buf
            const int nxt = cur ^ 1;
            float fx[8] = {xv0.x, xv0.y, xv0.z, xv0.w, xv1.x, xv1.y, xv1.z, xv1.w};
            ushort hh[8], ll[8];
#pragma unroll
            for (int i = 0; i < 8; ++i) {
                hh[i] = bf16_rne(fx[i]);
                ll[i] = bf16_rne(fx[i] - bf16_f32(hh[i]));
            }
            uint2 hv0 = {(uint)hh[0] | ((uint)hh[1] << 16), (uint)hh[2] | ((uint)hh[3] << 16)};
            uint2 lv0 = {(uint)ll[0] | ((uint)ll[1] << 16), (uint)ll[2] | ((uint)ll[3] << 16)};
            uint2 hv1 = {(uint)hh[4] | ((uint)hh[5] << 16), (uint)hh[6] | ((uint)hh[7] << 16)};
            uint2 lv1 = {(uint)ll[4] | ((uint)ll[5] << 16), (uint)ll[6] | ((uint)ll[7] << 16)};
            *(uint2*)&XH(nxt)[xd0] = hv0; *(uint2*)&XL(nxt)[xd0] = lv0;
            *(uint2*)&XH(nxt)[xd1] = hv1; *(uint2*)&XL(nxt)[xd1] = lv1;
            *(uint4*)&WH(nxt)[wd] = wv0;  *(uint4*)&WL(nxt)[wd] = wv1;
        }
        __syncthreads();
    }

    // ---- epilogue: cross-wave gather (part aliases XH/XL region, 16 KB) ----
    float* part = (float*)smem;   // [64 tokens][64 experts]
    const int trow = tb * 16 + (l >> 4) * 4;
    const int ec0 = eb * 32 + (l & 15);
#pragma unroll
    for (int r2 = 0; r2 < 4; ++r2) {
        part[(trow + r2) * 64 + ec0] = acc0[r2];
        part[(trow + r2) * 64 + ec0 + 16] = acc1[r2];
    }
    __syncthreads();

    const int e = l;
    const float be = b[e];
    for (int ti = 0; ti < 8; ++ti) {
        const int t = w * 8 + ti;
        float logit = part[t * 64 + e] + be;

        float v1, v2, v3; int i1, i2;
        for (int pass = 0; pass < 2; ++pass) {
            v1 = logit; i1 = e;
#pragma unroll
            for (int off = 32; off >= 1; off >>= 1) {
                float ov = __shfl_xor(v1, off, 64);
                int   oi = __shfl_xor(i1, off, 64);
                if (ov > v1 || (ov == v1 && oi < i1)) { v1 = ov; i1 = oi; }
            }
            v2 = (e == i1) ? -3.4e38f : logit;
            i2 = (e == i1) ? N_EXP : e;
#pragma unroll
            for (int off = 32; off >= 1; off >>= 1) {
                float ov = __shfl_xor(v2, off, 64);
                int   oi = __shfl_xor(i2, off, 64);
                if (ov > v2 || (ov == v2 && oi < i2)) { v2 = ov; i2 = oi; }
            }
            v3 = (e == i1 || e == i2) ? -3.4e38f : logit;
#pragma unroll
            for (int off = 32; off >= 1; off >>= 1) {
                float ov = __shfl_xor(v3, off, 64);
                v3 = (ov > v3) ? ov : v3;
            }
            if (pass == 1) break;
            const bool risky = (v1 - v2 < DELTA) || (v2 - v3 < DELTA);
            if (!risky) break;
            // exact fp32 recompute of candidate experts (wave-uniform path)
            unsigned long long cm = __ballot(logit >= v2 - DELTA2);
            const float* xr = x + (size_t)(tokBase + t) * C_IN;
            while (cm) {
                const int ce = __ffsll((unsigned long long)cm) - 1;
                cm &= cm - 1;
                const float* wr = Wf + (size_t)ce * C_IN;
                float p = 0.f;
#pragma unroll 8
                for (int i = 0; i < 32; ++i)
                    p = fmaf(xr[l + 64 * i], wr[l + 64 * i], p);
#pragma unroll
                for (int off = 32; off >= 1; off >>= 1)
                    p += __shfl_xor(p, off, 64);
                if (e == ce) logit = p + be;
            }
        }

        float ex = expf(logit - v1);
        float ssum = ex;
#pragma unroll
        for (int off = 32; off >= 1; off >>= 1)
            ssum += __shfl_xor(ssum, off, 64);
        const float inv = 1.0f / ssum;
        const float p1 = inv;
        const float p2 = expf(v2 - v1) * inv;
        const float o = (e == i1) ? p1 : ((e == i2) ? p2 : 0.0f);
        out[(size_t)(tokBase + t) * N_EXP + e] = o;
    }
}

extern "C" void kernel_launch(void* const* d_in, const int* in_sizes, int n_in,
                              void* d_out, int out_size, void* d_ws, size_t ws_size,
                              hipStream_t stream) {
    const float* x = (const float*)d_in[0];   // [4,4096,2048]
    const float* W = (const float*)d_in[1];   // [64,2048]
    const float* b = (const float*)d_in[2];   // [64]
    float* out = (float*)d_out;               // [4,4096,64]

    ushort* wh = (ushort*)d_ws;               // [64][2048] bf16 hi
    ushort* wl = wh + N_EXP * C_IN;           // [64][2048] bf16 lo (512 KB total)

    conv_w_kernel<<<512, 256, 0, stream>>>(W, wh, wl);

    const int tokens = in_sizes[0] / C_IN;    // 16384
    const int grid = tokens / TPB;            // 256
    topk_gate_kernel<<<grid, 512, 0, stream>>>(x, W, b, wh, wl, out);
}